// Round 14
// baseline (243.818 us; speedup 1.0000x reference)
//
#include <hip/hip_runtime.h>
#include <hip/hip_bf16.h>

typedef __attribute__((ext_vector_type(4))) float f32x4;
typedef __attribute__((ext_vector_type(8))) short s16x8;
typedef __attribute__((ext_vector_type(4))) short s16x4;

#define DEVINL __device__ __forceinline__

static constexpr int BB = 32, TT = 1024, DD = 512, EE = 256, VV = 50257, EXTRA = 200;
static constexpr int D2 = 1024;           // 2*D
static constexpr int VE = VV + EXTRA;     // 50457
static constexpr long MM = (long)BB * TT; // 32768
static constexpr int NBLK = 786;          // k_logits blocks

DEVINL unsigned short f2bf(float x) {
    union { float f; unsigned int u; } c; c.f = x;
    unsigned int u = c.u;
    u += 0x7fffu + ((u >> 16) & 1u);   // round-to-nearest-even
    return (unsigned short)(u >> 16);
}
DEVINL float bf2f(unsigned short h) {
    union { unsigned int u; float f; } c; c.u = ((unsigned int)h) << 16;
    return c.f;
}
DEVINL float sigmoidf_(float x) { return 1.0f / (1.0f + __expf(-x)); }
DEVINL float tanh_fast(float x) {
    x = fminf(15.f, fmaxf(-15.f, x));
    float e = __expf(2.f * x);
    return (e - 1.f) / (e + 1.f);
}
DEVINL void gl16(const void* g, void* l) {  // 16B global->LDS direct (dest: wave base + lane*16)
    __builtin_amdgcn_global_load_lds((__attribute__((address_space(1))) void*)g,
                                     (__attribute__((address_space(3))) void*)l, 16, 0, 0);
}

// ---------------------------------------------------------------- K0: fused prep
__global__ __launch_bounds__(256) void k_prep(const float* __restrict__ Wh,
                                              const float* __restrict__ enc,
                                              unsigned short* __restrict__ WhT,
                                              unsigned short* __restrict__ encswz) {
    __shared__ float tile[32][33];
    const int bid = blockIdx.x, tid = threadIdx.x;
    if (bid < 1024) {
        int n0 = (bid & 31) * 32, k0 = (bid >> 5) * 32;
        int col = tid & 31, row = tid >> 5;   // 32 x 8
        #pragma unroll
        for (int i = 0; i < 4; i++)
            tile[row + i * 8][col] = Wh[(long)(k0 + row + i * 8) * D2 + n0 + col];
        __syncthreads();
        #pragma unroll
        for (int i = 0; i < 4; i++) {
            int n = n0 + row + i * 8;
            int kcol = (k0 + col) ^ ((n & 7) << 3);
            WhT[(long)n * D2 + kcol] = f2bf(tile[col][row + i * 8]);
        }
    } else {
        long idx = (long)(bid - 1024) * 256 + tid;   // 16384 enc blocks
        int m  = (int)(idx >> 7);
        int k2 = (int)(idx & 127) * 8;
        int s  = (m & 7) << 3;
        const float* src = enc + (long)m * 1024 + (k2 ^ s);
        f32x4 a = *(const f32x4*)src;
        f32x4 b = *(const f32x4*)(src + 4);
        s16x8 h;
        h[0] = (short)f2bf(a[0]); h[1] = (short)f2bf(a[1]); h[2] = (short)f2bf(a[2]); h[3] = (short)f2bf(a[3]);
        h[4] = (short)f2bf(b[0]); h[5] = (short)f2bf(b[1]); h[6] = (short)f2bf(b[2]); h[7] = (short)f2bf(b[3]);
        *(s16x8*)(encswz + (long)m * 1024 + k2) = h;
    }
}

// ---------------------------------------------------------------- K1: x = [pcv|emb] @ W_gx + b_gx
__global__ __launch_bounds__(512) void k_x(
    const int* __restrict__ dec_in, const float* __restrict__ pcv,
    const float* __restrict__ embt, const float* __restrict__ Wgx,
    const float* __restrict__ bgx, float* __restrict__ xbuf) {
    __shared__ float xs[1280];
    __shared__ float sred[8][64];
    int b = blockIdx.x, n0 = blockIdx.y * 64;     // grid (32,4)
    int tid = threadIdx.x, nl = tid & 63, ks = tid >> 6;   // 8 k-slices x 160
    long er = (long)dec_in[b] * EE;
    for (int i = tid; i < 1280; i += 512)
        xs[i] = (i < 1024) ? pcv[b * 1024 + i] : embt[er + i - 1024];
    __syncthreads();
    float acc = 0.f;
    for (int k = ks * 160; k < ks * 160 + 160; ++k)
        acc += xs[k] * Wgx[(long)k * EE + n0 + nl];
    sred[ks][nl] = acc;
    __syncthreads();
    if (tid < 64) {
        int n = n0 + tid;
        float s = bgx[n];
        #pragma unroll
        for (int i = 0; i < 8; i++) s += sred[i][tid];
        xbuf[b * EE + n] = s;
    }
}

// ---------------------------------------------------------------- K2: LSTM cell (fused k-split)
__global__ __launch_bounds__(512) void k_lstm(
    const float* __restrict__ xbuf, const float* __restrict__ h0,
    const float* __restrict__ c0, const float* __restrict__ Wih,
    const float* __restrict__ Whh, const float* __restrict__ bih,
    const float* __restrict__ bhh, float* __restrict__ h1o,
    float* __restrict__ c1o, float* __restrict__ dechat) {
    __shared__ float xs[768];
    __shared__ float sred[4][8][64];
    int b = blockIdx.x, d0 = blockIdx.y * 64;     // grid (32,8)
    int tid = threadIdx.x, dl = tid & 63, ks = tid >> 6;   // 8 k-slices x 96
    for (int i = tid; i < 768; i += 512)
        xs[i] = (i < 256) ? xbuf[b * 256 + i] : h0[b * 512 + i - 256];
    __syncthreads();
    float a0 = 0, a1 = 0, a2 = 0, a3 = 0;
    for (int k = ks * 96; k < ks * 96 + 96; ++k) {
        float xv = xs[k];
        const float* wr = (k < 256) ? (Wih + (long)k * 2048) : (Whh + (long)(k - 256) * 2048);
        a0 += xv * wr[d0 + dl];        a1 += xv * wr[512 + d0 + dl];
        a2 += xv * wr[1024 + d0 + dl]; a3 += xv * wr[1536 + d0 + dl];
    }
    sred[0][ks][dl] = a0; sred[1][ks][dl] = a1; sred[2][ks][dl] = a2; sred[3][ks][dl] = a3;
    __syncthreads();
    if (tid < 64) {
        int d = d0 + tid;
        float gi = bih[d] + bhh[d];
        float gf = bih[512 + d] + bhh[512 + d];
        float gg = bih[1024 + d] + bhh[1024 + d];
        float go = bih[1536 + d] + bhh[1536 + d];
        #pragma unroll
        for (int s = 0; s < 8; s++) {
            gi += sred[0][s][tid]; gf += sred[1][s][tid];
            gg += sred[2][s][tid]; go += sred[3][s][tid];
        }
        float c1 = sigmoidf_(gf) * c0[b * 512 + d] + sigmoidf_(gi) * tanh_fast(gg);
        float h1 = sigmoidf_(go) * tanh_fast(c1);
        h1o[b * 512 + d] = h1; c1o[b * 512 + d] = c1;
        dechat[b * 1024 + d] = h1; dechat[b * 1024 + 512 + d] = c1;
    }
}

// ---------------------------------------------------------------- K3: dec_feat = dec_hat @ W_s + b_s
__global__ __launch_bounds__(512) void k_decfeat(
    const float* __restrict__ dechat, const float* __restrict__ Ws,
    const float* __restrict__ bs, float* __restrict__ decfeat) {
    __shared__ float xs[1024];
    __shared__ float sred[8][64];
    int b = blockIdx.x, n0 = blockIdx.y * 64;     // grid (32,16)
    int tid = threadIdx.x, nl = tid & 63, ks = tid >> 6;   // 8 x 128
    for (int i = tid; i < 1024; i += 512) xs[i] = dechat[b * 1024 + i];
    __syncthreads();
    float acc = 0.f;
    for (int k = ks * 128; k < ks * 128 + 128; ++k)
        acc += xs[k] * Ws[(long)k * 1024 + n0 + nl];
    sred[ks][nl] = acc;
    __syncthreads();
    if (tid < 64) {
        int n = n0 + tid;
        float s = bs[n];
        #pragma unroll
        for (int i = 0; i < 8; i++) s += sred[i][tid];
        decfeat[b * 1024 + n] = s;
    }
}

// ---------------------------------------------------------------- K4: fused attention scores, 128x128 tiles
// (m92/m103 measured optimum tile for the 2-barrier gl16 structure: 128^2 = 912 TF vs 128x256 = 823)
__global__ __launch_bounds__(512) void k_scores(
    const unsigned short* __restrict__ encswz, const unsigned short* __restrict__ whtswz,
    const float* __restrict__ decfeat, const float* __restrict__ cov,
    const float* __restrict__ Wc, const float* __restrict__ vvec,
    float* __restrict__ scorep) {
    __shared__ __align__(16) unsigned short As[128 * 64];   // 16 KB
    __shared__ __align__(16) unsigned short Bs[128 * 64];   // 16 KB
    __shared__ float sred[4][128];                          // 2 KB -> 34 KB total, 4 blocks/CU
    const int tid = threadIdx.x;
    const int lane = tid & 63, wave = tid >> 6;
    const int wid = __builtin_amdgcn_readfirstlane(wave);
    const int g = lane >> 4, c = lane & 15;
    const int wm = wave >> 2, wn = wave & 3;   // 2m x 4n waves over 128m x 128n (per wave 64x32)

    // XCD-chunked decode: 2048 blocks = 8 xcd x (32 mt x 8 nt); nt-siblings adjacent
    const int bid = blockIdx.x;
    const int xcd = bid & 7, t = bid >> 3;
    const int mt = xcd * 32 + (t >> 3), nt = t & 7;
    const long m0 = (long)mt * 128;
    const int n0 = nt * 128;
    const int bblk = mt >> 3;                  // batch row

    // staging: per wave 16 rows of A and 16 rows of B (2 gl16 each)
    const int arow = wid * 16 + (lane >> 3);
    const int axo  = (lane & 7) * 8;
    unsigned short* aBase = &As[wid * 1024];
    unsigned short* bBase = &Bs[wid * 1024];

    f32x4 acc[4][2];
    #pragma unroll
    for (int i = 0; i < 4; i++)
        #pragma unroll
        for (int j = 0; j < 2; j++) acc[i][j] = (f32x4){0.f, 0.f, 0.f, 0.f};

    const int sx = (c & 7) << 3;               // read-side swizzle

    for (int kt = 0; kt < 16; ++kt) {
        const int k0 = kt * 64;
        __syncthreads();
        gl16(encswz + (m0 + arow) * 1024 + k0 + axo,            aBase);
        gl16(encswz + (m0 + arow + 8) * 1024 + k0 + axo,        aBase + 512);
        gl16(whtswz + (long)(n0 + arow) * 1024 + k0 + axo,      bBase);
        gl16(whtswz + (long)(n0 + arow + 8) * 1024 + k0 + axo,  bBase + 512);
        __syncthreads();                       // drains vmcnt(0)
        #pragma unroll
        for (int kk = 0; kk < 2; ++kk) {
            const int kse = (kk * 32 + g * 8) ^ sx;
            s16x8 af[4], bfj[2];
            #pragma unroll
            for (int i = 0; i < 4; i++) af[i] = *(const s16x8*)&As[(wm * 64 + i * 16 + c) * 64 + kse];
            #pragma unroll
            for (int j = 0; j < 2; j++) bfj[j] = *(const s16x8*)&Bs[(wn * 32 + j * 16 + c) * 64 + kse];
            #pragma unroll
            for (int i = 0; i < 4; i++)
                #pragma unroll
                for (int j = 0; j < 2; j++)
                    acc[i][j] = __builtin_amdgcn_mfma_f32_16x16x32_bf16(af[i], bfj[j], acc[i][j], 0, 0, 0);
        }
    }
    // fused epilogue: v-weighted tanh partial sums (wave covers 32 n-cols)
    float dfv[2], wcv[2], vvj[2];
    #pragma unroll
    for (int j = 0; j < 2; j++) {
        int col = n0 + wn * 32 + j * 16 + c;
        dfv[j] = decfeat[bblk * D2 + col];
        wcv[j] = Wc[col];
        vvj[j] = vvec[col];
    }
    float sAcc[4][4];
    #pragma unroll
    for (int i = 0; i < 4; i++) {
        #pragma unroll
        for (int r = 0; r < 4; r++) {
            const long m = m0 + wm * 64 + i * 16 + g * 4 + r;
            const float covm = cov[m];
            float su = 0.f;
            #pragma unroll
            for (int j = 0; j < 2; j++) {
                float e = acc[i][j][r] + dfv[j] + covm * wcv[j];
                su += tanh_fast(e) * vvj[j];
            }
            su += __shfl_xor(su, 1); su += __shfl_xor(su, 2);
            su += __shfl_xor(su, 4); su += __shfl_xor(su, 8);
            sAcc[i][r] = su;
        }
    }
    if (c == 0) {
        #pragma unroll
        for (int i = 0; i < 4; i++)
            #pragma unroll
            for (int r = 0; r < 4; r++)
                sred[wn][wm * 64 + i * 16 + g * 4 + r] = sAcc[i][r];
    }
    __syncthreads();
    if (tid < 128)
        scorep[(long)nt * MM + m0 + tid] = sred[0][tid] + sred[1][tid] + sred[2][tid] + sred[3][tid];
}

// ---------------------------------------------------------------- K5: fused softmax + context partials (8 slabs)
__global__ __launch_bounds__(256) void k_ctx(
    const float* __restrict__ scorep, const float* __restrict__ mask,
    const float* __restrict__ cov, const unsigned short* __restrict__ encswz,
    float* __restrict__ att, float* __restrict__ covn, float* __restrict__ part) {
    int b = blockIdx.x, tc = blockIdx.y;
    int tid = threadIdx.x;
    __shared__ float sm[8];
    __shared__ float attL[1024];
    float sv[4];
    float mx = -1e30f;
    #pragma unroll
    for (int i = 0; i < 4; i++) {
        long idx = (long)b * TT + tid + 256 * i;
        float s8 = 0.f;
        #pragma unroll
        for (int p = 0; p < 8; p++) s8 += scorep[(long)p * MM + idx];
        sv[i] = s8;
        mx = fmaxf(mx, sv[i]);
    }
    for (int o = 32; o; o >>= 1) mx = fmaxf(mx, __shfl_xor(mx, o));
    if ((tid & 63) == 0) sm[tid >> 6] = mx;
    __syncthreads();
    mx = fmaxf(fmaxf(sm[0], sm[1]), fmaxf(sm[2], sm[3]));
    __syncthreads();
    float e[4]; float s = 0.f;
    #pragma unroll
    for (int i = 0; i < 4; i++) { e[i] = __expf(sv[i] - mx); s += e[i]; }
    for (int o = 32; o; o >>= 1) s += __shfl_xor(s, o);
    if ((tid & 63) == 0) sm[tid >> 6] = s;
    __syncthreads();
    s = sm[0] + sm[1] + sm[2] + sm[3];
    __syncthreads();
    float inv = 1.f / s;
    float am[4]; float s2 = 0.f;
    #pragma unroll
    for (int i = 0; i < 4; i++) { am[i] = e[i] * inv * mask[b * TT + tid + 256 * i]; s2 += am[i]; }
    for (int o = 32; o; o >>= 1) s2 += __shfl_xor(s2, o);
    if ((tid & 63) == 0) sm[tid >> 6] = s2;
    __syncthreads();
    s2 = sm[0] + sm[1] + sm[2] + sm[3];
    float inv2 = 1.f / s2;
    #pragma unroll
    for (int i = 0; i < 4; i++) {
        int t = tid + 256 * i;
        float a = am[i] * inv2;
        attL[t] = a;
        if (tc == 0) {
            att[b * TT + t] = a;
            covn[b * TT + t] = cov[b * TT + t] + a;
        }
    }
    __syncthreads();
    int d8 = (tid & 127) * 8;
    int tofs = tid >> 7;
    float a0 = 0, a1 = 0, a2 = 0, a3 = 0, a4 = 0, a5 = 0, a6 = 0, a7 = 0;
    for (int t = tc * 64 + tofs; t < tc * 64 + 64; t += 2) {
        float a = attL[t];
        int sx = (t & 7) << 3;
        const unsigned short* ep = encswz + ((long)b * TT + t) * D2 + (d8 ^ sx);
        s16x8 ev = *(const s16x8*)ep;
        a0 += a * bf2f((unsigned short)ev[0]); a1 += a * bf2f((unsigned short)ev[1]);
        a2 += a * bf2f((unsigned short)ev[2]); a3 += a * bf2f((unsigned short)ev[3]);
        a4 += a * bf2f((unsigned short)ev[4]); a5 += a * bf2f((unsigned short)ev[5]);
        a6 += a * bf2f((unsigned short)ev[6]); a7 += a * bf2f((unsigned short)ev[7]);
    }
    float* pp = part + (long)(tc * 2 + tofs) * BB * D2 + b * D2 + d8;
    pp[0] = a0; pp[1] = a1; pp[2] = a2; pp[3] = a3;
    pp[4] = a4; pp[5] = a5; pp[6] = a6; pp[7] = a7;
}

// ---------------------------------------------------------------- K6: fused ctx-reduce + p_gen + hidden
__global__ __launch_bounds__(512) void k_hidden2(
    const float* __restrict__ part, const float* __restrict__ h1,
    const float* __restrict__ dechat, const float* __restrict__ xbuf,
    const float* __restrict__ Wpg, const float* __restrict__ bpg,
    const float* __restrict__ Wv1, const float* __restrict__ bv1,
    float* __restrict__ ctx, float* __restrict__ pgen,
    unsigned short* __restrict__ hbf) {
    __shared__ float xs[1536];
    __shared__ float sred[8][64];
    int b = blockIdx.x, n0 = blockIdx.y * 64;
    int tid = threadIdx.x, nl = tid & 63, ks = tid >> 6;
    for (int i = tid; i < 512; i += 512) xs[i] = h1[b * 512 + i];
    #pragma unroll
    for (int d = tid; d < 1024; d += 512) {
        float s = 0.f;
        #pragma unroll
        for (int p = 0; p < 32; p++) s += part[(long)p * BB * D2 + b * D2 + d];
        xs[512 + d] = s;
        if (blockIdx.y == 0) ctx[b * D2 + d] = s;
    }
    __syncthreads();
    if (blockIdx.y == 0) {
        float pacc = xs[512 + tid] * Wpg[tid] + dechat[b * D2 + tid] * Wpg[D2 + tid]
                   + xs[1024 + tid] * Wpg[512 + tid] + dechat[b * D2 + 512 + tid] * Wpg[D2 + 512 + tid];
        if (tid < EE) pacc += xbuf[b * EE + tid] * Wpg[2 * D2 + tid];
        for (int o = 32; o; o >>= 1) pacc += __shfl_xor(pacc, o);
        __shared__ float psum[8];
        if ((tid & 63) == 0) psum[tid >> 6] = pacc;
        __syncthreads();
        if (tid == 0) {
            float t = 0.f;
            #pragma unroll
            for (int i = 0; i < 8; i++) t += psum[i];
            pgen[b] = sigmoidf_(t + bpg[0]);
        }
        __syncthreads();
    }
    float acc = 0.f;
    for (int k = ks * 192; k < ks * 192 + 192; ++k)
        acc += xs[k] * Wv1[(long)k * 512 + n0 + nl];
    sred[ks][nl] = acc;
    __syncthreads();
    if (tid < 64) {
        int n = n0 + tid;
        float s = bv1[n];
        #pragma unroll
        for (int i = 0; i < 8; i++) s += sred[i][tid];
        hbf[b * 512 + n] = f2bf(s);
    }
}

// ---------------------------------------------------------------- K7: logits GEMM + per-block softmax stats
__global__ __launch_bounds__(256) void k_logits(const unsigned short* __restrict__ hbf,
                                                const float* __restrict__ Wv2,
                                                const float* __restrict__ bv2,
                                                float* __restrict__ logits,
                                                float* __restrict__ bsm,
                                                float* __restrict__ bss) {
    constexpr int PITCH = 136;
    __shared__ __align__(16) unsigned short Bs[64 * PITCH];   // 17 KB
    __shared__ float sm_[4][16], ss_[4][16];
    const int tid = threadIdx.x;
    const int lane = tid & 63, wave = tid >> 6;
    const int g = lane >> 4, c = lane & 15;
    const int wm = wave >> 1, wn = wave & 1;
    const long v0 = (long)blockIdx.x * 64;
    const bool tail = (v0 + 64 > VV);

    const int vg = tid & 15, kr = tid >> 4;

    f32x4 acc[2];
    acc[0] = (f32x4){0.f, 0.f, 0.f, 0.f};
    acc[1] = (f32x4){0.f, 0.f, 0.f, 0.f};
    const int sxr = (c & 7) << 3;

    f32x4 wa[4], wb[4];
    #pragma unroll
    for (int pi = 0; pi < 4; ++pi) {
        const int ka = kr * 8 + pi * 2;
        if (!tail) {
            wa[pi] = *(const f32x4*)&Wv2[(long)ka * VV + v0 + vg * 4];
            wb[pi] = *(const f32x4*)&Wv2[(long)(ka + 1) * VV + v0 + vg * 4];
        } else {
            #pragma unroll
            for (int j = 0; j < 4; j++) {
                long v = v0 + vg * 4 + j;
                long vs = (v < VV) ? v : (VV - 1);
                wa[pi][j] = Wv2[(long)ka * VV + vs];
                wb[pi][j] = Wv2[(long)(ka + 1) * VV + vs];
            }
        }
    }
    #pragma unroll
    for (int kt = 0; kt < 4; ++kt) {
        const int k0 = kt * 128;
        __syncthreads();
        #pragma unroll
        for (int pi = 0; pi < 4; ++pi) {
            #pragma unroll
            for (int j = 0; j < 4; j++) {
                int vl = vg * 4 + j;
                int ks = (kr * 8 + pi * 2) ^ ((vl & 7) << 3);
                unsigned int pack = (unsigned int)f2bf(wa[pi][j]) | ((unsigned int)f2bf(wb[pi][j]) << 16);
                *(unsigned int*)&Bs[vl * PITCH + ks] = pack;
            }
        }
        if (kt < 3) {
            const int k1 = (kt + 1) * 128;
            #pragma unroll
            for (int pi = 0; pi < 4; ++pi) {
                const int ka = k1 + kr * 8 + pi * 2;
                if (!tail) {
                    wa[pi] = *(const f32x4*)&Wv2[(long)ka * VV + v0 + vg * 4];
                    wb[pi] = *(const f32x4*)&Wv2[(long)(ka + 1) * VV + v0 + vg * 4];
                } else {
                    #pragma unroll
                    for (int j = 0; j < 4; j++) {
                        long v = v0 + vg * 4 + j;
                        long vs = (v < VV) ? v : (VV - 1);
                        wa[pi][j] = Wv2[(long)ka * VV + vs];
                        wb[pi][j] = Wv2[(long)(ka + 1) * VV + vs];
                    }
                }
            }
        }
        __syncthreads();
        #pragma unroll
        for (int kk = 0; kk < 4; ++kk) {
            const int koff = kk * 32 + g * 8;
            const int kse = koff ^ sxr;
            s16x8 af = *(const s16x8*)&hbf[(wm * 16 + c) * 512 + k0 + koff];
            s16x8 bf0 = *(const s16x8*)&Bs[(wn * 32 + c) * PITCH + kse];
            s16x8 bf1 = *(const s16x8*)&Bs[(wn * 32 + 16 + c) * PITCH + kse];
            acc[0] = __builtin_amdgcn_mfma_f32_16x16x32_bf16(af, bf0, acc[0], 0, 0, 0);
            acc[1] = __builtin_amdgcn_mfma_f32_16x16x32_bf16(af, bf1, acc[1], 0, 0, 0);
        }
    }
    float lv[2][4];
    #pragma unroll
    for (int j = 0; j < 2; j++) {
        long v = v0 + wn * 32 + j * 16 + c;
        bool valid = (v < VV);
        float bvv = valid ? bv2[v] : 0.f;
        #pragma unroll
        for (int r = 0; r < 4; r++) {
            float val = acc[j][r] + bvv;
            if (valid) {
                int b = wm * 16 + g * 4 + r;
                logits[(long)b * VV + v] = val;
                lv[j][r] = val;
            } else {
                lv[j][r] = -1e30f;
            }
        }
    }
    float mrow[4], srow[4];
    #pragma unroll
    for (int r = 0; r < 4; r++) {
        float m = fmaxf(lv[0][r], lv[1][r]);
        m = fmaxf(m, __shfl_xor(m, 1)); m = fmaxf(m, __shfl_xor(m, 2));
        m = fmaxf(m, __shfl_xor(m, 4)); m = fmaxf(m, __shfl_xor(m, 8));
        float s = __expf(lv[0][r] - m) + __expf(lv[1][r] - m);
        s += __shfl_xor(s, 1); s += __shfl_xor(s, 2);
        s += __shfl_xor(s, 4); s += __shfl_xor(s, 8);
        mrow[r] = m; srow[r] = s;
    }
    if (c == 0) {
        #pragma unroll
        for (int r = 0; r < 4; r++) { sm_[wave][g * 4 + r] = mrow[r]; ss_[wave][g * 4 + r] = srow[r]; }
    }
    __syncthreads();
    if (tid < 32) {
        int b = tid;
        int w0 = (b >> 4) * 2, ridx = b & 15;
        float mA = sm_[w0][ridx], mB = sm_[w0 + 1][ridx];
        float sA = ss_[w0][ridx], sB = ss_[w0 + 1][ridx];
        float m = fmaxf(mA, mB);
        float s = sA * __expf(mA - m) + sB * __expf(mB - m);
        bsm[(long)b * NBLK + blockIdx.x] = m;
        bss[(long)b * NBLK + blockIdx.x] = s;
    }
}

// ---------------------------------------------------------------- K8: stats combine + vocab write + slice-owned scatter
// grid (32,25) x 512. Each block merges the 786 block-stats, writes its 2048-col slice,
// then applies the pointer-scatter entries whose target falls in its own slice.
__global__ __launch_bounds__(512) void k_vocab(
    const float* __restrict__ logits, const float* __restrict__ bsm,
    const float* __restrict__ bss, const float* __restrict__ pgen,
    const float* __restrict__ extraz, const float* __restrict__ att,
    const int* __restrict__ eiv, float* __restrict__ out0) {
    int b = blockIdx.x;
    int v0 = blockIdx.y * 2048;
    int tid = threadIdx.x;
    __shared__ float smm[8], sms[8], fin[2];
    float m = -1e30f, s = 0.f;
    #pragma unroll
    for (int it = 0; it < 2; ++it) {
        int i = tid + it * 512;
        if (i < NBLK) {
            float mi = bsm[(long)b * NBLK + i], si = bss[(long)b * NBLK + i];
            float nm = fmaxf(m, mi);
            s = s * __expf(m - nm) + si * __expf(mi - nm);
            m = nm;
        }
    }
    for (int o = 32; o; o >>= 1) {
        float m2 = __shfl_xor(m, o), s2 = __shfl_xor(s, o);
        float nm = fmaxf(m, m2);
        s = s * __expf(m - nm) + s2 * __expf(m2 - nm);
        m = nm;
    }
    if ((tid & 63) == 0) { smm[tid >> 6] = m; sms[tid >> 6] = s; }
    __syncthreads();
    if (tid == 0) {
        float fm = smm[0], fs = sms[0];
        #pragma unroll
        for (int i = 1; i < 8; i++) {
            float nm = fmaxf(fm, smm[i]);
            fs = fs * __expf(fm - nm) + sms[i] * __expf(smm[i] - nm);
            fm = nm;
        }
        fin[0] = fm; fin[1] = pgen[b] / fs;
    }
    __syncthreads();
    float mx = fin[0], inv = fin[1];
    float pg = pgen[b];
    const float* lr = logits + (long)b * VV;
    float* orow = out0 + (long)b * VE;
    #pragma unroll
    for (int i = 0; i < 4; i++) {
        int v = v0 + i * 512 + tid;
        if (v < VV)      orow[v] = __expf(lr[v] - mx) * inv;
        else if (v < VE) orow[v] = extraz[b * EXTRA + (v - VV)];
    }
    __syncthreads();
    // slice-owned pointer scatter (targets in [v0, v0+2048) only; slices disjoint)
    int vend = v0 + 2048;
    #pragma unroll
    for (int it = 0; it < 2; ++it) {
        int t = tid + it * 512;
        int tgt = eiv[b * TT + t];
        if (tgt >= v0 && tgt < vend) {
            float a = (1.f - pg) * att[b * TT + t];
            atomicAdd(orow + tgt, a);
        }
    }
}

// ================================================================ host
extern "C" void kernel_launch(void* const* d_in, const int* in_sizes, int n_in,
                              void* d_out, int out_size, void* d_ws, size_t ws_size,
                              hipStream_t stream) {
    const int*   dec_in = (const int*)d_in[0];
    const float* h0     = (const float*)d_in[1];
    const float* c0     = (const float*)d_in[2];
    const float* enc    = (const float*)d_in[3];
    const float* mask   = (const float*)d_in[4];
    const float* pcv    = (const float*)d_in[5];
    const float* cov    = (const float*)d_in[6];
    const float* extraz = (const float*)d_in[7];
    const int*   eiv    = (const int*)d_in[8];
    /* d_in[9] = step (unused, training path) */
    const float* embt   = (const float*)d_in[10];
    const float* Wgx    = (const float*)d_in[11];
    const float* bgx    = (const float*)d_in[12];
    const float* Wih    = (const float*)d_in[13];
    const float* Whh    = (const float*)d_in[14];
    const float* bih    = (const float*)d_in[15];
    const float* bhh    = (const float*)d_in[16];
    const float* Wh     = (const float*)d_in[17];
    const float* Wc     = (const float*)d_in[18];
    const float* Ws     = (const float*)d_in[19];
    const float* bs     = (const float*)d_in[20];
    const float* vv     = (const float*)d_in[21];
    const float* Wpg    = (const float*)d_in[22];
    const float* bpg    = (const float*)d_in[23];
    const float* Wv1    = (const float*)d_in[24];
    const float* bv1    = (const float*)d_in[25];
    const float* Wv2    = (const float*)d_in[26];
    const float* bv2    = (const float*)d_in[27];

    float* out = (float*)d_out;
    float* out_vd  = out;
    float* out_h1  = out + (long)BB * VE;
    float* out_c1  = out_h1 + BB * DD;
    float* out_ctx = out_c1 + BB * DD;
    float* out_att = out_ctx + BB * D2;
    float* out_cov = out_att + BB * TT;

    char* p = (char*)d_ws;
    unsigned short* whtswz = (unsigned short*)p; p += (size_t)D2 * D2 * 2;      // 2 MB
    float* xbuf    = (float*)p;  p += (size_t)BB * EE * 4;
    float* dechat  = (float*)p;  p += (size_t)BB * D2 * 4;
    float* decfeat = (float*)p;  p += (size_t)BB * D2 * 4;
    float* scorep  = (float*)p;  p += (size_t)8 * MM * 4;                        // 1 MB (8 partials)
    float* pgen    = (float*)p;  p += 256;
    unsigned short* hbf = (unsigned short*)p; p += (size_t)BB * DD * 2 + 256;    // 32 KB
    float* bsm     = (float*)p;  p += (size_t)BB * NBLK * 4;                     // 100 KB
    float* bss     = (float*)p;  p += (size_t)BB * NBLK * 4;                     // 100 KB
    float* ctxpart = (float*)p;  p += (size_t)32 * BB * D2 * 4;                  // 4 MB
    float* logits  = (float*)p;  p += (size_t)BB * VV * 4;                       // 6.43 MB
    unsigned short* encswz = (unsigned short*)p; p += (size_t)MM * D2 * 2;       // 67.1 MB

    k_prep<<<1024 + 16384, 256, 0, stream>>>(Wh, enc, whtswz, encswz);
    k_x<<<dim3(BB, 4), 512, 0, stream>>>(dec_in, pcv, embt, Wgx, bgx, xbuf);
    k_lstm<<<dim3(BB, 8), 512, 0, stream>>>(xbuf, h0, c0, Wih, Whh, bih, bhh, out_h1, out_c1, dechat);
    k_decfeat<<<dim3(BB, 16), 512, 0, stream>>>(dechat, Ws, bs, decfeat);
    k_scores<<<2048, 512, 0, stream>>>(encswz, whtswz, decfeat, cov, Wc, vv, scorep);
    k_ctx<<<dim3(BB, 16), 256, 0, stream>>>(scorep, mask, cov, encswz, out_att, out_cov, ctxpart);
    k_hidden2<<<dim3(BB, 8), 512, 0, stream>>>(ctxpart, out_h1, dechat, xbuf, Wpg, bpg,
                                               Wv1, bv1, out_ctx, pgen, hbf);
    k_logits<<<NBLK, 256, 0, stream>>>(hbf, Wv2, bv2, logits, bsm, bss);
    k_vocab<<<dim3(BB, 25), 512, 0, stream>>>(logits, bsm, bss, pgen, extraz, out_att, eiv, out_vd);
}

// Round 15
// 234.765 us; speedup vs baseline: 1.0386x; 1.0386x over previous
//
#include <hip/hip_runtime.h>
#include <hip/hip_bf16.h>

typedef __attribute__((ext_vector_type(4))) float f32x4;
typedef __attribute__((ext_vector_type(8))) short s16x8;
typedef __attribute__((ext_vector_type(4))) short s16x4;

#define DEVINL __device__ __forceinline__

static constexpr int BB = 32, TT = 1024, DD = 512, EE = 256, VV = 50257, EXTRA = 200;
static constexpr int D2 = 1024;           // 2*D
static constexpr int VE = VV + EXTRA;     // 50457
static constexpr long MM = (long)BB * TT; // 32768
static constexpr int NBLK = 786;          // k_logits blocks

DEVINL unsigned short f2bf(float x) {
    union { float f; unsigned int u; } c; c.f = x;
    unsigned int u = c.u;
    u += 0x7fffu + ((u >> 16) & 1u);   // round-to-nearest-even
    return (unsigned short)(u >> 16);
}
DEVINL float bf2f(unsigned short h) {
    union { unsigned int u; float f; } c; c.u = ((unsigned int)h) << 16;
    return c.f;
}
DEVINL float sigmoidf_(float x) { return 1.0f / (1.0f + __expf(-x)); }
DEVINL float tanh_fast(float x) {
    x = fminf(15.f, fmaxf(-15.f, x));
    float e = __expf(2.f * x);
    return (e - 1.f) / (e + 1.f);
}
DEVINL void gl16(const void* g, void* l) {  // 16B global->LDS direct (dest: wave base + lane*16)
    __builtin_amdgcn_global_load_lds((__attribute__((address_space(1))) void*)g,
                                     (__attribute__((address_space(3))) void*)l, 16, 0, 0);
}

// ---------------------------------------------------------------- K0: fused prep
__global__ __launch_bounds__(256) void k_prep(const float* __restrict__ Wh,
                                              const float* __restrict__ enc,
                                              unsigned short* __restrict__ WhT,
                                              unsigned short* __restrict__ encswz) {
    __shared__ float tile[32][33];
    const int bid = blockIdx.x, tid = threadIdx.x;
    if (bid < 1024) {
        int n0 = (bid & 31) * 32, k0 = (bid >> 5) * 32;
        int col = tid & 31, row = tid >> 5;   // 32 x 8
        #pragma unroll
        for (int i = 0; i < 4; i++)
            tile[row + i * 8][col] = Wh[(long)(k0 + row + i * 8) * D2 + n0 + col];
        __syncthreads();
        #pragma unroll
        for (int i = 0; i < 4; i++) {
            int n = n0 + row + i * 8;
            int kcol = (k0 + col) ^ ((n & 7) << 3);
            WhT[(long)n * D2 + kcol] = f2bf(tile[col][row + i * 8]);
        }
    } else {
        long idx = (long)(bid - 1024) * 256 + tid;   // 16384 enc blocks
        int m  = (int)(idx >> 7);
        int k2 = (int)(idx & 127) * 8;
        int s  = (m & 7) << 3;
        const float* src = enc + (long)m * 1024 + (k2 ^ s);
        f32x4 a = *(const f32x4*)src;
        f32x4 b = *(const f32x4*)(src + 4);
        s16x8 h;
        h[0] = (short)f2bf(a[0]); h[1] = (short)f2bf(a[1]); h[2] = (short)f2bf(a[2]); h[3] = (short)f2bf(a[3]);
        h[4] = (short)f2bf(b[0]); h[5] = (short)f2bf(b[1]); h[6] = (short)f2bf(b[2]); h[7] = (short)f2bf(b[3]);
        *(s16x8*)(encswz + (long)m * 1024 + k2) = h;
    }
}

// ---------------------------------------------------------------- K1: x = [pcv|emb] @ W_gx + b_gx
__global__ __launch_bounds__(512) void k_x(
    const int* __restrict__ dec_in, const float* __restrict__ pcv,
    const float* __restrict__ embt, const float* __restrict__ Wgx,
    const float* __restrict__ bgx, float* __restrict__ xbuf) {
    __shared__ float xs[1280];
    __shared__ float sred[8][64];
    int b = blockIdx.x, n0 = blockIdx.y * 64;     // grid (32,4)
    int tid = threadIdx.x, nl = tid & 63, ks = tid >> 6;   // 8 k-slices x 160
    long er = (long)dec_in[b] * EE;
    for (int i = tid; i < 1280; i += 512)
        xs[i] = (i < 1024) ? pcv[b * 1024 + i] : embt[er + i - 1024];
    __syncthreads();
    float acc = 0.f;
    for (int k = ks * 160; k < ks * 160 + 160; ++k)
        acc += xs[k] * Wgx[(long)k * EE + n0 + nl];
    sred[ks][nl] = acc;
    __syncthreads();
    if (tid < 64) {
        int n = n0 + tid;
        float s = bgx[n];
        #pragma unroll
        for (int i = 0; i < 8; i++) s += sred[i][tid];
        xbuf[b * EE + n] = s;
    }
}

// ---------------------------------------------------------------- K2: LSTM cell (fused k-split)
__global__ __launch_bounds__(512) void k_lstm(
    const float* __restrict__ xbuf, const float* __restrict__ h0,
    const float* __restrict__ c0, const float* __restrict__ Wih,
    const float* __restrict__ Whh, const float* __restrict__ bih,
    const float* __restrict__ bhh, float* __restrict__ h1o,
    float* __restrict__ c1o, float* __restrict__ dechat) {
    __shared__ float xs[768];
    __shared__ float sred[4][8][64];
    int b = blockIdx.x, d0 = blockIdx.y * 64;     // grid (32,8)
    int tid = threadIdx.x, dl = tid & 63, ks = tid >> 6;   // 8 k-slices x 96
    for (int i = tid; i < 768; i += 512)
        xs[i] = (i < 256) ? xbuf[b * 256 + i] : h0[b * 512 + i - 256];
    __syncthreads();
    float a0 = 0, a1 = 0, a2 = 0, a3 = 0;
    for (int k = ks * 96; k < ks * 96 + 96; ++k) {
        float xv = xs[k];
        const float* wr = (k < 256) ? (Wih + (long)k * 2048) : (Whh + (long)(k - 256) * 2048);
        a0 += xv * wr[d0 + dl];        a1 += xv * wr[512 + d0 + dl];
        a2 += xv * wr[1024 + d0 + dl]; a3 += xv * wr[1536 + d0 + dl];
    }
    sred[0][ks][dl] = a0; sred[1][ks][dl] = a1; sred[2][ks][dl] = a2; sred[3][ks][dl] = a3;
    __syncthreads();
    if (tid < 64) {
        int d = d0 + tid;
        float gi = bih[d] + bhh[d];
        float gf = bih[512 + d] + bhh[512 + d];
        float gg = bih[1024 + d] + bhh[1024 + d];
        float go = bih[1536 + d] + bhh[1536 + d];
        #pragma unroll
        for (int s = 0; s < 8; s++) {
            gi += sred[0][s][tid]; gf += sred[1][s][tid];
            gg += sred[2][s][tid]; go += sred[3][s][tid];
        }
        float c1 = sigmoidf_(gf) * c0[b * 512 + d] + sigmoidf_(gi) * tanh_fast(gg);
        float h1 = sigmoidf_(go) * tanh_fast(c1);
        h1o[b * 512 + d] = h1; c1o[b * 512 + d] = c1;
        dechat[b * 1024 + d] = h1; dechat[b * 1024 + 512 + d] = c1;
    }
}

// ---------------------------------------------------------------- K3: dec_feat = dec_hat @ W_s + b_s
__global__ __launch_bounds__(512) void k_decfeat(
    const float* __restrict__ dechat, const float* __restrict__ Ws,
    const float* __restrict__ bs, float* __restrict__ decfeat) {
    __shared__ float xs[1024];
    __shared__ float sred[8][64];
    int b = blockIdx.x, n0 = blockIdx.y * 64;     // grid (32,16)
    int tid = threadIdx.x, nl = tid & 63, ks = tid >> 6;   // 8 x 128
    for (int i = tid; i < 1024; i += 512) xs[i] = dechat[b * 1024 + i];
    __syncthreads();
    float acc = 0.f;
    for (int k = ks * 128; k < ks * 128 + 128; ++k)
        acc += xs[k] * Ws[(long)k * 1024 + n0 + nl];
    sred[ks][nl] = acc;
    __syncthreads();
    if (tid < 64) {
        int n = n0 + tid;
        float s = bs[n];
        #pragma unroll
        for (int i = 0; i < 8; i++) s += sred[i][tid];
        decfeat[b * 1024 + n] = s;
    }
}

// ---------------------------------------------------------------- K4: fused attention scores (R13 proven 128x256)
__global__ __launch_bounds__(512) void k_scores(
    const unsigned short* __restrict__ encswz, const unsigned short* __restrict__ whtswz,
    const float* __restrict__ decfeat, const float* __restrict__ cov,
    const float* __restrict__ Wc, const float* __restrict__ vvec,
    float* __restrict__ scorep) {
    __shared__ __align__(16) unsigned short As[128 * 64];   // 16 KB, linear, data pre-swizzled
    __shared__ __align__(16) unsigned short Bs[256 * 64];   // 32 KB
    __shared__ float sred[4][128];                          // total 50 KB -> 3 blocks/CU
    const int tid = threadIdx.x;
    const int lane = tid & 63, wave = tid >> 6;
    const int wid = __builtin_amdgcn_readfirstlane(wave);
    const int g = lane >> 4, c = lane & 15;
    const int wm = wave >> 2, wn = wave & 3;   // 2 x 4 waves over 128m x 256n

    const int bid = blockIdx.x;
    const int xcd = bid & 7, t = bid >> 3;
    const int mt = xcd * 32 + (t >> 2), nt = t & 3;
    const long m0 = (long)mt * 128;
    const int n0 = nt * 256;
    const int bblk = mt >> 3;                  // batch row

    const int arow = wid * 16 + (lane >> 3);
    const int axo  = (lane & 7) * 8;
    const int brow = wid * 32 + (lane >> 3);
    unsigned short* aBase = &As[wid * 1024];
    unsigned short* bBase = &Bs[wid * 2048];

    f32x4 acc[4][4];
    #pragma unroll
    for (int i = 0; i < 4; i++)
        #pragma unroll
        for (int j = 0; j < 4; j++) acc[i][j] = (f32x4){0.f, 0.f, 0.f, 0.f};

    const int sx = (c & 7) << 3;               // read-side swizzle

    for (int kt = 0; kt < 16; ++kt) {
        const int k0 = kt * 64;
        __syncthreads();
        gl16(encswz + (m0 + arow) * 1024 + k0 + axo,       aBase);
        gl16(encswz + (m0 + arow + 8) * 1024 + k0 + axo,   aBase + 512);
        gl16(whtswz + (long)(n0 + brow) * 1024 + k0 + axo,        bBase);
        gl16(whtswz + (long)(n0 + brow + 8) * 1024 + k0 + axo,    bBase + 512);
        gl16(whtswz + (long)(n0 + brow + 16) * 1024 + k0 + axo,   bBase + 1024);
        gl16(whtswz + (long)(n0 + brow + 24) * 1024 + k0 + axo,   bBase + 1536);
        __syncthreads();                       // drains vmcnt(0)
        #pragma unroll
        for (int kk = 0; kk < 2; ++kk) {
            const int kse = (kk * 32 + g * 8) ^ sx;
            s16x8 af[4], bfj[4];
            #pragma unroll
            for (int i = 0; i < 4; i++) af[i] = *(const s16x8*)&As[(wm * 64 + i * 16 + c) * 64 + kse];
            #pragma unroll
            for (int j = 0; j < 4; j++) bfj[j] = *(const s16x8*)&Bs[(wn * 64 + j * 16 + c) * 64 + kse];
            #pragma unroll
            for (int i = 0; i < 4; i++)
                #pragma unroll
                for (int j = 0; j < 4; j++)
                    acc[i][j] = __builtin_amdgcn_mfma_f32_16x16x32_bf16(af[i], bfj[j], acc[i][j], 0, 0, 0);
        }
    }
    float dfv[4], wcv[4], vvj[4];
    #pragma unroll
    for (int j = 0; j < 4; j++) {
        int col = n0 + wn * 64 + j * 16 + c;
        dfv[j] = decfeat[bblk * D2 + col];
        wcv[j] = Wc[col];
        vvj[j] = vvec[col];
    }
    float sAcc[4][4];
    #pragma unroll
    for (int i = 0; i < 4; i++) {
        #pragma unroll
        for (int r = 0; r < 4; r++) {
            const long m = m0 + wm * 64 + i * 16 + g * 4 + r;
            const float covm = cov[m];
            float su = 0.f;
            #pragma unroll
            for (int j = 0; j < 4; j++) {
                float e = acc[i][j][r] + dfv[j] + covm * wcv[j];
                su += tanh_fast(e) * vvj[j];
            }
            su += __shfl_xor(su, 1); su += __shfl_xor(su, 2);
            su += __shfl_xor(su, 4); su += __shfl_xor(su, 8);
            sAcc[i][r] = su;
        }
    }
    if (c == 0) {
        #pragma unroll
        for (int i = 0; i < 4; i++)
            #pragma unroll
            for (int r = 0; r < 4; r++)
                sred[wn][wm * 64 + i * 16 + g * 4 + r] = sAcc[i][r];
    }
    __syncthreads();
    if (tid < 128)
        scorep[(long)nt * MM + m0 + tid] = sred[0][tid] + sred[1][tid] + sred[2][tid] + sred[3][tid];
}

// ---------------------------------------------------------------- K5: fused softmax + context partials (4 partials)
__global__ __launch_bounds__(256) void k_ctx(
    const float* __restrict__ scorep, const float* __restrict__ mask,
    const float* __restrict__ cov, const unsigned short* __restrict__ encswz,
    float* __restrict__ att, float* __restrict__ covn, float* __restrict__ part) {
    int b = blockIdx.x, tc = blockIdx.y;
    int tid = threadIdx.x;
    __shared__ float sm[8];
    __shared__ float attL[1024];
    float sv[4];
    float mx = -1e30f;
    #pragma unroll
    for (int i = 0; i < 4; i++) {
        long idx = (long)b * TT + tid + 256 * i;
        sv[i] = scorep[idx] + scorep[MM + idx] + scorep[2 * MM + idx] + scorep[3 * MM + idx];
        mx = fmaxf(mx, sv[i]);
    }
    for (int o = 32; o; o >>= 1) mx = fmaxf(mx, __shfl_xor(mx, o));
    if ((tid & 63) == 0) sm[tid >> 6] = mx;
    __syncthreads();
    mx = fmaxf(fmaxf(sm[0], sm[1]), fmaxf(sm[2], sm[3]));
    __syncthreads();
    float e[4]; float s = 0.f;
    #pragma unroll
    for (int i = 0; i < 4; i++) { e[i] = __expf(sv[i] - mx); s += e[i]; }
    for (int o = 32; o; o >>= 1) s += __shfl_xor(s, o);
    if ((tid & 63) == 0) sm[tid >> 6] = s;
    __syncthreads();
    s = sm[0] + sm[1] + sm[2] + sm[3];
    __syncthreads();
    float inv = 1.f / s;
    float am[4]; float s2 = 0.f;
    #pragma unroll
    for (int i = 0; i < 4; i++) { am[i] = e[i] * inv * mask[b * TT + tid + 256 * i]; s2 += am[i]; }
    for (int o = 32; o; o >>= 1) s2 += __shfl_xor(s2, o);
    if ((tid & 63) == 0) sm[tid >> 6] = s2;
    __syncthreads();
    s2 = sm[0] + sm[1] + sm[2] + sm[3];
    float inv2 = 1.f / s2;
    #pragma unroll
    for (int i = 0; i < 4; i++) {
        int t = tid + 256 * i;
        float a = am[i] * inv2;
        attL[t] = a;
        if (tc == 0) {
            att[b * TT + t] = a;
            covn[b * TT + t] = cov[b * TT + t] + a;
        }
    }
    __syncthreads();
    int d8 = (tid & 127) * 8;
    int tofs = tid >> 7;
    float a0 = 0, a1 = 0, a2 = 0, a3 = 0, a4 = 0, a5 = 0, a6 = 0, a7 = 0;
    for (int t = tc * 64 + tofs; t < tc * 64 + 64; t += 2) {
        float a = attL[t];
        int sx = (t & 7) << 3;
        const unsigned short* ep = encswz + ((long)b * TT + t) * D2 + (d8 ^ sx);
        s16x8 ev = *(const s16x8*)ep;
        a0 += a * bf2f((unsigned short)ev[0]); a1 += a * bf2f((unsigned short)ev[1]);
        a2 += a * bf2f((unsigned short)ev[2]); a3 += a * bf2f((unsigned short)ev[3]);
        a4 += a * bf2f((unsigned short)ev[4]); a5 += a * bf2f((unsigned short)ev[5]);
        a6 += a * bf2f((unsigned short)ev[6]); a7 += a * bf2f((unsigned short)ev[7]);
    }
    float* pp = part + (long)(tc * 2 + tofs) * BB * D2 + b * D2 + d8;
    pp[0] = a0; pp[1] = a1; pp[2] = a2; pp[3] = a3;
    pp[4] = a4; pp[5] = a5; pp[6] = a6; pp[7] = a7;
}

// ---------------------------------------------------------------- K6: fused ctx-reduce + p_gen + hidden
__global__ __launch_bounds__(512) void k_hidden2(
    const float* __restrict__ part, const float* __restrict__ h1,
    const float* __restrict__ dechat, const float* __restrict__ xbuf,
    const float* __restrict__ Wpg, const float* __restrict__ bpg,
    const float* __restrict__ Wv1, const float* __restrict__ bv1,
    float* __restrict__ ctx, float* __restrict__ pgen,
    unsigned short* __restrict__ hbf) {
    __shared__ float xs[1536];
    __shared__ float sred[8][64];
    int b = blockIdx.x, n0 = blockIdx.y * 64;
    int tid = threadIdx.x, nl = tid & 63, ks = tid >> 6;
    for (int i = tid; i < 512; i += 512) xs[i] = h1[b * 512 + i];
    #pragma unroll
    for (int d = tid; d < 1024; d += 512) {
        float s = 0.f;
        #pragma unroll
        for (int p = 0; p < 32; p++) s += part[(long)p * BB * D2 + b * D2 + d];
        xs[512 + d] = s;
        if (blockIdx.y == 0) ctx[b * D2 + d] = s;
    }
    __syncthreads();
    if (blockIdx.y == 0) {
        float pacc = xs[512 + tid] * Wpg[tid] + dechat[b * D2 + tid] * Wpg[D2 + tid]
                   + xs[1024 + tid] * Wpg[512 + tid] + dechat[b * D2 + 512 + tid] * Wpg[D2 + 512 + tid];
        if (tid < EE) pacc += xbuf[b * EE + tid] * Wpg[2 * D2 + tid];
        for (int o = 32; o; o >>= 1) pacc += __shfl_xor(pacc, o);
        __shared__ float psum[8];
        if ((tid & 63) == 0) psum[tid >> 6] = pacc;
        __syncthreads();
        if (tid == 0) {
            float t = 0.f;
            #pragma unroll
            for (int i = 0; i < 8; i++) t += psum[i];
            pgen[b] = sigmoidf_(t + bpg[0]);
        }
        __syncthreads();
    }
    float acc = 0.f;
    for (int k = ks * 192; k < ks * 192 + 192; ++k)
        acc += xs[k] * Wv1[(long)k * 512 + n0 + nl];
    sred[ks][nl] = acc;
    __syncthreads();
    if (tid < 64) {
        int n = n0 + tid;
        float s = bv1[n];
        #pragma unroll
        for (int i = 0; i < 8; i++) s += sred[i][tid];
        hbf[b * 512 + n] = f2bf(s);
    }
}

// ---------------------------------------------------------------- K7: logits GEMM + per-block softmax stats
__global__ __launch_bounds__(256) void k_logits(const unsigned short* __restrict__ hbf,
                                                const float* __restrict__ Wv2,
                                                const float* __restrict__ bv2,
                                                float* __restrict__ logits,
                                                float* __restrict__ bsm,
                                                float* __restrict__ bss) {
    constexpr int PITCH = 136;
    __shared__ __align__(16) unsigned short Bs[64 * PITCH];   // 17 KB
    __shared__ float sm_[4][16], ss_[4][16];
    const int tid = threadIdx.x;
    const int lane = tid & 63, wave = tid >> 6;
    const int g = lane >> 4, c = lane & 15;
    const int wm = wave >> 1, wn = wave & 1;
    const long v0 = (long)blockIdx.x * 64;
    const bool tail = (v0 + 64 > VV);

    const int vg = tid & 15, kr = tid >> 4;

    f32x4 acc[2];
    acc[0] = (f32x4){0.f, 0.f, 0.f, 0.f};
    acc[1] = (f32x4){0.f, 0.f, 0.f, 0.f};
    const int sxr = (c & 7) << 3;

    f32x4 wa[4], wb[4];
    #pragma unroll
    for (int pi = 0; pi < 4; ++pi) {
        const int ka = kr * 8 + pi * 2;
        if (!tail) {
            wa[pi] = *(const f32x4*)&Wv2[(long)ka * VV + v0 + vg * 4];
            wb[pi] = *(const f32x4*)&Wv2[(long)(ka + 1) * VV + v0 + vg * 4];
        } else {
            #pragma unroll
            for (int j = 0; j < 4; j++) {
                long v = v0 + vg * 4 + j;
                long vs = (v < VV) ? v : (VV - 1);
                wa[pi][j] = Wv2[(long)ka * VV + vs];
                wb[pi][j] = Wv2[(long)(ka + 1) * VV + vs];
            }
        }
    }
    #pragma unroll
    for (int kt = 0; kt < 4; ++kt) {
        const int k0 = kt * 128;
        __syncthreads();
        #pragma unroll
        for (int pi = 0; pi < 4; ++pi) {
            #pragma unroll
            for (int j = 0; j < 4; j++) {
                int vl = vg * 4 + j;
                int ks = (kr * 8 + pi * 2) ^ ((vl & 7) << 3);
                unsigned int pack = (unsigned int)f2bf(wa[pi][j]) | ((unsigned int)f2bf(wb[pi][j]) << 16);
                *(unsigned int*)&Bs[vl * PITCH + ks] = pack;
            }
        }
        if (kt < 3) {
            const int k1 = (kt + 1) * 128;
            #pragma unroll
            for (int pi = 0; pi < 4; ++pi) {
                const int ka = k1 + kr * 8 + pi * 2;
                if (!tail) {
                    wa[pi] = *(const f32x4*)&Wv2[(long)ka * VV + v0 + vg * 4];
                    wb[pi] = *(const f32x4*)&Wv2[(long)(ka + 1) * VV + v0 + vg * 4];
                } else {
                    #pragma unroll
                    for (int j = 0; j < 4; j++) {
                        long v = v0 + vg * 4 + j;
                        long vs = (v < VV) ? v : (VV - 1);
                        wa[pi][j] = Wv2[(long)ka * VV + vs];
                        wb[pi][j] = Wv2[(long)(ka + 1) * VV + vs];
                    }
                }
            }
        }
        __syncthreads();
        #pragma unroll
        for (int kk = 0; kk < 4; ++kk) {
            const int koff = kk * 32 + g * 8;
            const int kse = koff ^ sxr;
            s16x8 af = *(const s16x8*)&hbf[(wm * 16 + c) * 512 + k0 + koff];
            s16x8 bf0 = *(const s16x8*)&Bs[(wn * 32 + c) * PITCH + kse];
            s16x8 bf1 = *(const s16x8*)&Bs[(wn * 32 + 16 + c) * PITCH + kse];
            acc[0] = __builtin_amdgcn_mfma_f32_16x16x32_bf16(af, bf0, acc[0], 0, 0, 0);
            acc[1] = __builtin_amdgcn_mfma_f32_16x16x32_bf16(af, bf1, acc[1], 0, 0, 0);
        }
    }
    float lv[2][4];
    #pragma unroll
    for (int j = 0; j < 2; j++) {
        long v = v0 + wn * 32 + j * 16 + c;
        bool valid = (v < VV);
        float bvv = valid ? bv2[v] : 0.f;
        #pragma unroll
        for (int r = 0; r < 4; r++) {
            float val = acc[j][r] + bvv;
            if (valid) {
                int b = wm * 16 + g * 4 + r;
                logits[(long)b * VV + v] = val;
                lv[j][r] = val;
            } else {
                lv[j][r] = -1e30f;
            }
        }
    }
    float mrow[4], srow[4];
    #pragma unroll
    for (int r = 0; r < 4; r++) {
        float m = fmaxf(lv[0][r], lv[1][r]);
        m = fmaxf(m, __shfl_xor(m, 1)); m = fmaxf(m, __shfl_xor(m, 2));
        m = fmaxf(m, __shfl_xor(m, 4)); m = fmaxf(m, __shfl_xor(m, 8));
        float s = __expf(lv[0][r] - m) + __expf(lv[1][r] - m);
        s += __shfl_xor(s, 1); s += __shfl_xor(s, 2);
        s += __shfl_xor(s, 4); s += __shfl_xor(s, 8);
        mrow[r] = m; srow[r] = s;
    }
    if (c == 0) {
        #pragma unroll
        for (int r = 0; r < 4; r++) { sm_[wave][g * 4 + r] = mrow[r]; ss_[wave][g * 4 + r] = srow[r]; }
    }
    __syncthreads();
    if (tid < 32) {
        int b = tid;
        int w0 = (b >> 4) * 2, ridx = b & 15;
        float mA = sm_[w0][ridx], mB = sm_[w0 + 1][ridx];
        float sA = ss_[w0][ridx], sB = ss_[w0 + 1][ridx];
        float m = fmaxf(mA, mB);
        float s = sA * __expf(mA - m) + sB * __expf(mB - m);
        bsm[(long)b * NBLK + blockIdx.x] = m;
        bss[(long)b * NBLK + blockIdx.x] = s;
    }
}

// ---------------------------------------------------------------- K8: stats combine + vocab write + slice-owned scatter
__global__ __launch_bounds__(512) void k_vocab(
    const float* __restrict__ logits, const float* __restrict__ bsm,
    const float* __restrict__ bss, const float* __restrict__ pgen,
    const float* __restrict__ extraz, const float* __restrict__ att,
    const int* __restrict__ eiv, float* __restrict__ out0) {
    int b = blockIdx.x;
    int v0 = blockIdx.y * 2048;
    int tid = threadIdx.x;
    __shared__ float smm[8], sms[8], fin[2];
    float m = -1e30f, s = 0.f;
    #pragma unroll
    for (int it = 0; it < 2; ++it) {
        int i = tid + it * 512;
        if (i < NBLK) {
            float mi = bsm[(long)b * NBLK + i], si = bss[(long)b * NBLK + i];
            float nm = fmaxf(m, mi);
            s = s * __expf(m - nm) + si * __expf(mi - nm);
            m = nm;
        }
    }
    for (int o = 32; o; o >>= 1) {
        float m2 = __shfl_xor(m, o), s2 = __shfl_xor(s, o);
        float nm = fmaxf(m, m2);
        s = s * __expf(m - nm) + s2 * __expf(m2 - nm);
        m = nm;
    }
    if ((tid & 63) == 0) { smm[tid >> 6] = m; sms[tid >> 6] = s; }
    __syncthreads();
    if (tid == 0) {
        float fm = smm[0], fs = sms[0];
        #pragma unroll
        for (int i = 1; i < 8; i++) {
            float nm = fmaxf(fm, smm[i]);
            fs = fs * __expf(fm - nm) + sms[i] * __expf(smm[i] - nm);
            fm = nm;
        }
        fin[0] = fm; fin[1] = pgen[b] / fs;
    }
    __syncthreads();
    float mx = fin[0], inv = fin[1];
    float pg = pgen[b];
    const float* lr = logits + (long)b * VV;
    float* orow = out0 + (long)b * VE;
    #pragma unroll
    for (int i = 0; i < 4; i++) {
        int v = v0 + i * 512 + tid;
        if (v < VV)      orow[v] = __expf(lr[v] - mx) * inv;
        else if (v < VE) orow[v] = extraz[b * EXTRA + (v - VV)];
    }
    __syncthreads();
    int vend = v0 + 2048;
    #pragma unroll
    for (int it = 0; it < 2; ++it) {
        int t = tid + it * 512;
        int tgt = eiv[b * TT + t];
        if (tgt >= v0 && tgt < vend) {
            float a = (1.f - pg) * att[b * TT + t];
            atomicAdd(orow + tgt, a);
        }
    }
}

// ================================================================ host
extern "C" void kernel_launch(void* const* d_in, const int* in_sizes, int n_in,
                              void* d_out, int out_size, void* d_ws, size_t ws_size,
                              hipStream_t stream) {
    const int*   dec_in = (const int*)d_in[0];
    const float* h0     = (const float*)d_in[1];
    const float* c0     = (const float*)d_in[2];
    const float* enc    = (const float*)d_in[3];
    const float* mask   = (const float*)d_in[4];
    const float* pcv    = (const float*)d_in[5];
    const float* cov    = (const float*)d_in[6];
    const float* extraz = (const float*)d_in[7];
    const int*   eiv    = (const int*)d_in[8];
    /* d_in[9] = step (unused, training path) */
    const float* embt   = (const float*)d_in[10];
    const float* Wgx    = (const float*)d_in[11];
    const float* bgx    = (const float*)d_in[12];
    const float* Wih    = (const float*)d_in[13];
    const float* Whh    = (const float*)d_in[14];
    const float* bih    = (const float*)d_in[15];
    const float* bhh    = (const float*)d_in[16];
    const float* Wh     = (const float*)d_in[17];
    const float* Wc     = (const float*)d_in[18];
    const float* Ws     = (const float*)d_in[19];
    const float* bs     = (const float*)d_in[20];
    const float* vv     = (const float*)d_in[21];
    const float* Wpg    = (const float*)d_in[22];
    const float* bpg    = (const float*)d_in[23];
    const float* Wv1    = (const float*)d_in[24];
    const float* bv1    = (const float*)d_in[25];
    const float* Wv2    = (const float*)d_in[26];
    const float* bv2    = (const float*)d_in[27];

    float* out = (float*)d_out;
    float* out_vd  = out;
    float* out_h1  = out + (long)BB * VE;
    float* out_c1  = out_h1 + BB * DD;
    float* out_ctx = out_c1 + BB * DD;
    float* out_att = out_ctx + BB * D2;
    float* out_cov = out_att + BB * TT;

    char* p = (char*)d_ws;
    unsigned short* whtswz = (unsigned short*)p; p += (size_t)D2 * D2 * 2;      // 2 MB
    float* xbuf    = (float*)p;  p += (size_t)BB * EE * 4;
    float* dechat  = (float*)p;  p += (size_t)BB * D2 * 4;
    float* decfeat = (float*)p;  p += (size_t)BB * D2 * 4;
    float* scorep  = (float*)p;  p += (size_t)4 * MM * 4;                        // 512 KB
    float* pgen    = (float*)p;  p += 256;
    unsigned short* hbf = (unsigned short*)p; p += (size_t)BB * DD * 2 + 256;    // 32 KB
    float* bsm     = (float*)p;  p += (size_t)BB * NBLK * 4;                     // 100 KB
    float* bss     = (float*)p;  p += (size_t)BB * NBLK * 4;                     // 100 KB
    float* ctxpart = (float*)p;  p += (size_t)32 * BB * D2 * 4;                  // 4 MB
    float* logits  = (float*)p;  p += (size_t)BB * VV * 4;                       // 6.43 MB
    unsigned short* encswz = (unsigned short*)p; p += (size_t)MM * D2 * 2;       // 67.1 MB

    k_prep<<<1024 + 16384, 256, 0, stream>>>(Wh, enc, whtswz, encswz);
    k_x<<<dim3(BB, 4), 512, 0, stream>>>(dec_in, pcv, embt, Wgx, bgx, xbuf);
    k_lstm<<<dim3(BB, 8), 512, 0, stream>>>(xbuf, h0, c0, Wih, Whh, bih, bhh, out_h1, out_c1, dechat);
    k_decfeat<<<dim3(BB, 16), 512, 0, stream>>>(dechat, Ws, bs, decfeat);
    k_scores<<<1024, 512, 0, stream>>>(encswz, whtswz, decfeat, cov, Wc, vv, scorep);
    k_ctx<<<dim3(BB, 16), 256, 0, stream>>>(scorep, mask, cov, encswz, out_att, out_cov, ctxpart);
    k_hidden2<<<dim3(BB, 8), 512, 0, stream>>>(ctxpart, out_h1, dechat, xbuf, Wpg, bpg,
                                               Wv1, bv1, out_ctx, pgen, hbf);
    k_logits<<<NBLK, 256, 0, stream>>>(hbf, Wv2, bv2, logits, bsm, bss);
    k_vocab<<<dim3(BB, 25), 512, 0, stream>>>(logits, bsm, bss, pgen, extraz, out_att, eiv, out_vd);
}

// Round 16
// 230.131 us; speedup vs baseline: 1.0595x; 1.0201x over previous
//
#include <hip/hip_runtime.h>
#include <hip/hip_bf16.h>

typedef __attribute__((ext_vector_type(4))) float f32x4;
typedef __attribute__((ext_vector_type(8))) short s16x8;
typedef __attribute__((ext_vector_type(4))) short s16x4;

#define DEVINL __device__ __forceinline__

static constexpr int BB = 32, TT = 1024, DD = 512, EE = 256, VV = 50257, EXTRA = 200;
static constexpr int D2 = 1024;           // 2*D
static constexpr int VE = VV + EXTRA;     // 50457
static constexpr long MM = (long)BB * TT; // 32768
static constexpr int NBLK = 786;          // k_logits blocks

DEVINL unsigned short f2bf(float x) {
    union { float f; unsigned int u; } c; c.f = x;
    unsigned int u = c.u;
    u += 0x7fffu + ((u >> 16) & 1u);   // round-to-nearest-even
    return (unsigned short)(u >> 16);
}
DEVINL float bf2f(unsigned short h) {
    union { unsigned int u; float f; } c; c.u = ((unsigned int)h) << 16;
    return c.f;
}
DEVINL float sigmoidf_(float x) { return 1.0f / (1.0f + __expf(-x)); }
DEVINL float tanh_fast(float x) {
    x = fminf(15.f, fmaxf(-15.f, x));
    float e = __expf(2.f * x);
    return (e - 1.f) / (e + 1.f);
}
DEVINL void gl16(const void* g, void* l) {  // 16B global->LDS direct (dest: wave base + lane*16)
    __builtin_amdgcn_global_load_lds((__attribute__((address_space(1))) void*)g,
                                     (__attribute__((address_space(3))) void*)l, 16, 0, 0);
}

// ---------------------------------------------------------------- K0: fused prep (+ k_x block range)
// bid <  1024          : whtswz[n][k] = bf16(Wh[k ^ ((n&7)<<3)][n])
// 1024 <= bid < 1152   : x = [pcv|emb] @ W_gx + b_gx  (b = (bid-1024)>>2, n0 = ((bid-1024)&3)*64)
// bid >= 1152          : encswz[m][k] = bf16(enc[m][k ^ ((m&7)<<3)])
__global__ __launch_bounds__(256) void k_prep(
    const float* __restrict__ Wh, const float* __restrict__ enc,
    const int* __restrict__ dec_in, const float* __restrict__ pcv,
    const float* __restrict__ embt, const float* __restrict__ Wgx,
    const float* __restrict__ bgx,
    unsigned short* __restrict__ WhT, unsigned short* __restrict__ encswz,
    float* __restrict__ xbuf) {
    const int bid = blockIdx.x, tid = threadIdx.x;
    if (bid < 1024) {
        __shared__ float tile[32][33];
        int n0 = (bid & 31) * 32, k0 = (bid >> 5) * 32;
        int col = tid & 31, row = tid >> 5;   // 32 x 8
        #pragma unroll
        for (int i = 0; i < 4; i++)
            tile[row + i * 8][col] = Wh[(long)(k0 + row + i * 8) * D2 + n0 + col];
        __syncthreads();
        #pragma unroll
        for (int i = 0; i < 4; i++) {
            int n = n0 + row + i * 8;
            int kcol = (k0 + col) ^ ((n & 7) << 3);
            WhT[(long)n * D2 + kcol] = f2bf(tile[col][row + i * 8]);
        }
    } else if (bid < 1152) {
        __shared__ float xs[1280];
        __shared__ float sred[4][64];
        int idx = bid - 1024;
        int b = idx >> 2, n0 = (idx & 3) * 64;
        int nl = tid & 63, ks = tid >> 6;     // 4 k-slices x 320
        long er = (long)dec_in[b] * EE;
        for (int i = tid; i < 1280; i += 256)
            xs[i] = (i < 1024) ? pcv[b * 1024 + i] : embt[er + i - 1024];
        __syncthreads();
        float acc = 0.f;
        for (int k = ks * 320; k < ks * 320 + 320; ++k)
            acc += xs[k] * Wgx[(long)k * EE + n0 + nl];
        sred[ks][nl] = acc;
        __syncthreads();
        if (tid < 64) {
            int n = n0 + tid;
            xbuf[b * EE + n] = sred[0][tid] + sred[1][tid] + sred[2][tid] + sred[3][tid] + bgx[n];
        }
    } else {
        long idx = (long)(bid - 1152) * 256 + tid;   // 16384 enc blocks
        int m  = (int)(idx >> 7);
        int k2 = (int)(idx & 127) * 8;
        int s  = (m & 7) << 3;
        const float* src = enc + (long)m * 1024 + (k2 ^ s);
        f32x4 a = *(const f32x4*)src;
        f32x4 b = *(const f32x4*)(src + 4);
        s16x8 h;
        h[0] = (short)f2bf(a[0]); h[1] = (short)f2bf(a[1]); h[2] = (short)f2bf(a[2]); h[3] = (short)f2bf(a[3]);
        h[4] = (short)f2bf(b[0]); h[5] = (short)f2bf(b[1]); h[6] = (short)f2bf(b[2]); h[7] = (short)f2bf(b[3]);
        *(s16x8*)(encswz + (long)m * 1024 + k2) = h;
    }
}

// ---------------------------------------------------------------- K2: LSTM cell (fused k-split)
__global__ __launch_bounds__(512) void k_lstm(
    const float* __restrict__ xbuf, const float* __restrict__ h0,
    const float* __restrict__ c0, const float* __restrict__ Wih,
    const float* __restrict__ Whh, const float* __restrict__ bih,
    const float* __restrict__ bhh, float* __restrict__ h1o,
    float* __restrict__ c1o, float* __restrict__ dechat) {
    __shared__ float xs[768];
    __shared__ float sred[4][8][64];
    int b = blockIdx.x, d0 = blockIdx.y * 64;     // grid (32,8)
    int tid = threadIdx.x, dl = tid & 63, ks = tid >> 6;   // 8 k-slices x 96
    for (int i = tid; i < 768; i += 512)
        xs[i] = (i < 256) ? xbuf[b * 256 + i] : h0[b * 512 + i - 256];
    __syncthreads();
    float a0 = 0, a1 = 0, a2 = 0, a3 = 0;
    for (int k = ks * 96; k < ks * 96 + 96; ++k) {
        float xv = xs[k];
        const float* wr = (k < 256) ? (Wih + (long)k * 2048) : (Whh + (long)(k - 256) * 2048);
        a0 += xv * wr[d0 + dl];        a1 += xv * wr[512 + d0 + dl];
        a2 += xv * wr[1024 + d0 + dl]; a3 += xv * wr[1536 + d0 + dl];
    }
    sred[0][ks][dl] = a0; sred[1][ks][dl] = a1; sred[2][ks][dl] = a2; sred[3][ks][dl] = a3;
    __syncthreads();
    if (tid < 64) {
        int d = d0 + tid;
        float gi = bih[d] + bhh[d];
        float gf = bih[512 + d] + bhh[512 + d];
        float gg = bih[1024 + d] + bhh[1024 + d];
        float go = bih[1536 + d] + bhh[1536 + d];
        #pragma unroll
        for (int s = 0; s < 8; s++) {
            gi += sred[0][s][tid]; gf += sred[1][s][tid];
            gg += sred[2][s][tid]; go += sred[3][s][tid];
        }
        float c1 = sigmoidf_(gf) * c0[b * 512 + d] + sigmoidf_(gi) * tanh_fast(gg);
        float h1 = sigmoidf_(go) * tanh_fast(c1);
        h1o[b * 512 + d] = h1; c1o[b * 512 + d] = c1;
        dechat[b * 1024 + d] = h1; dechat[b * 1024 + 512 + d] = c1;
    }
}

// ---------------------------------------------------------------- K3: dec_feat = dec_hat @ W_s + b_s
__global__ __launch_bounds__(512) void k_decfeat(
    const float* __restrict__ dechat, const float* __restrict__ Ws,
    const float* __restrict__ bs, float* __restrict__ decfeat) {
    __shared__ float xs[1024];
    __shared__ float sred[8][64];
    int b = blockIdx.x, n0 = blockIdx.y * 64;     // grid (32,16)
    int tid = threadIdx.x, nl = tid & 63, ks = tid >> 6;   // 8 x 128
    for (int i = tid; i < 1024; i += 512) xs[i] = dechat[b * 1024 + i];
    __syncthreads();
    float acc = 0.f;
    for (int k = ks * 128; k < ks * 128 + 128; ++k)
        acc += xs[k] * Ws[(long)k * 1024 + n0 + nl];
    sred[ks][nl] = acc;
    __syncthreads();
    if (tid < 64) {
        int n = n0 + tid;
        float s = bs[n];
        #pragma unroll
        for (int i = 0; i < 8; i++) s += sred[i][tid];
        decfeat[b * 1024 + n] = s;
    }
}

// ---------------------------------------------------------------- K4: fused attention scores (proven 128x256)
__global__ __launch_bounds__(512) void k_scores(
    const unsigned short* __restrict__ encswz, const unsigned short* __restrict__ whtswz,
    const float* __restrict__ decfeat, const float* __restrict__ cov,
    const float* __restrict__ Wc, const float* __restrict__ vvec,
    float* __restrict__ scorep) {
    __shared__ __align__(16) unsigned short As[128 * 64];   // 16 KB, linear, data pre-swizzled
    __shared__ __align__(16) unsigned short Bs[256 * 64];   // 32 KB
    __shared__ float sred[4][128];                          // total 50 KB -> 3 blocks/CU
    const int tid = threadIdx.x;
    const int lane = tid & 63, wave = tid >> 6;
    const int wid = __builtin_amdgcn_readfirstlane(wave);
    const int g = lane >> 4, c = lane & 15;
    const int wm = wave >> 2, wn = wave & 3;   // 2 x 4 waves over 128m x 256n

    const int bid = blockIdx.x;
    const int xcd = bid & 7, t = bid >> 3;
    const int mt = xcd * 32 + (t >> 2), nt = t & 3;
    const long m0 = (long)mt * 128;
    const int n0 = nt * 256;
    const int bblk = mt >> 3;                  // batch row

    const int arow = wid * 16 + (lane >> 3);
    const int axo  = (lane & 7) * 8;
    const int brow = wid * 32 + (lane >> 3);
    unsigned short* aBase = &As[wid * 1024];
    unsigned short* bBase = &Bs[wid * 2048];

    f32x4 acc[4][4];
    #pragma unroll
    for (int i = 0; i < 4; i++)
        #pragma unroll
        for (int j = 0; j < 4; j++) acc[i][j] = (f32x4){0.f, 0.f, 0.f, 0.f};

    const int sx = (c & 7) << 3;               // read-side swizzle

    for (int kt = 0; kt < 16; ++kt) {
        const int k0 = kt * 64;
        __syncthreads();
        gl16(encswz + (m0 + arow) * 1024 + k0 + axo,       aBase);
        gl16(encswz + (m0 + arow + 8) * 1024 + k0 + axo,   aBase + 512);
        gl16(whtswz + (long)(n0 + brow) * 1024 + k0 + axo,        bBase);
        gl16(whtswz + (long)(n0 + brow + 8) * 1024 + k0 + axo,    bBase + 512);
        gl16(whtswz + (long)(n0 + brow + 16) * 1024 + k0 + axo,   bBase + 1024);
        gl16(whtswz + (long)(n0 + brow + 24) * 1024 + k0 + axo,   bBase + 1536);
        __syncthreads();                       // drains vmcnt(0)
        #pragma unroll
        for (int kk = 0; kk < 2; ++kk) {
            const int kse = (kk * 32 + g * 8) ^ sx;
            s16x8 af[4], bfj[4];
            #pragma unroll
            for (int i = 0; i < 4; i++) af[i] = *(const s16x8*)&As[(wm * 64 + i * 16 + c) * 64 + kse];
            #pragma unroll
            for (int j = 0; j < 4; j++) bfj[j] = *(const s16x8*)&Bs[(wn * 64 + j * 16 + c) * 64 + kse];
            #pragma unroll
            for (int i = 0; i < 4; i++)
                #pragma unroll
                for (int j = 0; j < 4; j++)
                    acc[i][j] = __builtin_amdgcn_mfma_f32_16x16x32_bf16(af[i], bfj[j], acc[i][j], 0, 0, 0);
        }
    }
    float dfv[4], wcv[4], vvj[4];
    #pragma unroll
    for (int j = 0; j < 4; j++) {
        int col = n0 + wn * 64 + j * 16 + c;
        dfv[j] = decfeat[bblk * D2 + col];
        wcv[j] = Wc[col];
        vvj[j] = vvec[col];
    }
    float sAcc[4][4];
    #pragma unroll
    for (int i = 0; i < 4; i++) {
        #pragma unroll
        for (int r = 0; r < 4; r++) {
            const long m = m0 + wm * 64 + i * 16 + g * 4 + r;
            const float covm = cov[m];
            float su = 0.f;
            #pragma unroll
            for (int j = 0; j < 4; j++) {
                float e = acc[i][j][r] + dfv[j] + covm * wcv[j];
                su += tanh_fast(e) * vvj[j];
            }
            su += __shfl_xor(su, 1); su += __shfl_xor(su, 2);
            su += __shfl_xor(su, 4); su += __shfl_xor(su, 8);
            sAcc[i][r] = su;
        }
    }
    if (c == 0) {
        #pragma unroll
        for (int i = 0; i < 4; i++)
            #pragma unroll
            for (int r = 0; r < 4; r++)
                sred[wn][wm * 64 + i * 16 + g * 4 + r] = sAcc[i][r];
    }
    __syncthreads();
    if (tid < 128)
        scorep[(long)nt * MM + m0 + tid] = sred[0][tid] + sred[1][tid] + sred[2][tid] + sred[3][tid];
}

// ---------------------------------------------------------------- K5: fused softmax + context partials
__global__ __launch_bounds__(256) void k_ctx(
    const float* __restrict__ scorep, const float* __restrict__ mask,
    const float* __restrict__ cov, const unsigned short* __restrict__ encswz,
    float* __restrict__ att, float* __restrict__ covn, float* __restrict__ part) {
    int b = blockIdx.x, tc = blockIdx.y;
    int tid = threadIdx.x;
    __shared__ float sm[8];
    __shared__ float attL[1024];
    float sv[4];
    float mx = -1e30f;
    #pragma unroll
    for (int i = 0; i < 4; i++) {
        long idx = (long)b * TT + tid + 256 * i;
        sv[i] = scorep[idx] + scorep[MM + idx] + scorep[2 * MM + idx] + scorep[3 * MM + idx];
        mx = fmaxf(mx, sv[i]);
    }
    for (int o = 32; o; o >>= 1) mx = fmaxf(mx, __shfl_xor(mx, o));
    if ((tid & 63) == 0) sm[tid >> 6] = mx;
    __syncthreads();
    mx = fmaxf(fmaxf(sm[0], sm[1]), fmaxf(sm[2], sm[3]));
    __syncthreads();
    float e[4]; float s = 0.f;
    #pragma unroll
    for (int i = 0; i < 4; i++) { e[i] = __expf(sv[i] - mx); s += e[i]; }
    for (int o = 32; o; o >>= 1) s += __shfl_xor(s, o);
    if ((tid & 63) == 0) sm[tid >> 6] = s;
    __syncthreads();
    s = sm[0] + sm[1] + sm[2] + sm[3];
    __syncthreads();
    float inv = 1.f / s;
    float am[4]; float s2 = 0.f;
    #pragma unroll
    for (int i = 0; i < 4; i++) { am[i] = e[i] * inv * mask[b * TT + tid + 256 * i]; s2 += am[i]; }
    for (int o = 32; o; o >>= 1) s2 += __shfl_xor(s2, o);
    if ((tid & 63) == 0) sm[tid >> 6] = s2;
    __syncthreads();
    s2 = sm[0] + sm[1] + sm[2] + sm[3];
    float inv2 = 1.f / s2;
    #pragma unroll
    for (int i = 0; i < 4; i++) {
        int t = tid + 256 * i;
        float a = am[i] * inv2;
        attL[t] = a;
        if (tc == 0) {
            att[b * TT + t] = a;
            covn[b * TT + t] = cov[b * TT + t] + a;
        }
    }
    __syncthreads();
    int d8 = (tid & 127) * 8;
    int tofs = tid >> 7;
    float a0 = 0, a1 = 0, a2 = 0, a3 = 0, a4 = 0, a5 = 0, a6 = 0, a7 = 0;
    for (int t = tc * 64 + tofs; t < tc * 64 + 64; t += 2) {
        float a = attL[t];
        int sx = (t & 7) << 3;
        const unsigned short* ep = encswz + ((long)b * TT + t) * D2 + (d8 ^ sx);
        s16x8 ev = *(const s16x8*)ep;
        a0 += a * bf2f((unsigned short)ev[0]); a1 += a * bf2f((unsigned short)ev[1]);
        a2 += a * bf2f((unsigned short)ev[2]); a3 += a * bf2f((unsigned short)ev[3]);
        a4 += a * bf2f((unsigned short)ev[4]); a5 += a * bf2f((unsigned short)ev[5]);
        a6 += a * bf2f((unsigned short)ev[6]); a7 += a * bf2f((unsigned short)ev[7]);
    }
    float* pp = part + (long)(tc * 2 + tofs) * BB * D2 + b * D2 + d8;
    pp[0] = a0; pp[1] = a1; pp[2] = a2; pp[3] = a3;
    pp[4] = a4; pp[5] = a5; pp[6] = a6; pp[7] = a7;
}

// ---------------------------------------------------------------- K6: fused ctx-reduce + p_gen + hidden
__global__ __launch_bounds__(512) void k_hidden2(
    const float* __restrict__ part, const float* __restrict__ h1,
    const float* __restrict__ dechat, const float* __restrict__ xbuf,
    const float* __restrict__ Wpg, const float* __restrict__ bpg,
    const float* __restrict__ Wv1, const float* __restrict__ bv1,
    float* __restrict__ ctx, float* __restrict__ pgen,
    unsigned short* __restrict__ hbf) {
    __shared__ float xs[1536];
    __shared__ float sred[8][64];
    int b = blockIdx.x, n0 = blockIdx.y * 64;
    int tid = threadIdx.x, nl = tid & 63, ks = tid >> 6;
    for (int i = tid; i < 512; i += 512) xs[i] = h1[b * 512 + i];
    #pragma unroll
    for (int d = tid; d < 1024; d += 512) {
        float s = 0.f;
        #pragma unroll
        for (int p = 0; p < 32; p++) s += part[(long)p * BB * D2 + b * D2 + d];
        xs[512 + d] = s;
        if (blockIdx.y == 0) ctx[b * D2 + d] = s;
    }
    __syncthreads();
    if (blockIdx.y == 0) {
        float pacc = xs[512 + tid] * Wpg[tid] + dechat[b * D2 + tid] * Wpg[D2 + tid]
                   + xs[1024 + tid] * Wpg[512 + tid] + dechat[b * D2 + 512 + tid] * Wpg[D2 + 512 + tid];
        if (tid < EE) pacc += xbuf[b * EE + tid] * Wpg[2 * D2 + tid];
        for (int o = 32; o; o >>= 1) pacc += __shfl_xor(pacc, o);
        __shared__ float psum[8];
        if ((tid & 63) == 0) psum[tid >> 6] = pacc;
        __syncthreads();
        if (tid == 0) {
            float t = 0.f;
            #pragma unroll
            for (int i = 0; i < 8; i++) t += psum[i];
            pgen[b] = sigmoidf_(t + bpg[0]);
        }
        __syncthreads();
    }
    float acc = 0.f;
    for (int k = ks * 192; k < ks * 192 + 192; ++k)
        acc += xs[k] * Wv1[(long)k * 512 + n0 + nl];
    sred[ks][nl] = acc;
    __syncthreads();
    if (tid < 64) {
        int n = n0 + tid;
        float s = bv1[n];
        #pragma unroll
        for (int i = 0; i < 8; i++) s += sred[i][tid];
        hbf[b * 512 + n] = f2bf(s);
    }
}

// ---------------------------------------------------------------- K7: logits GEMM + per-block softmax stats
__global__ __launch_bounds__(256) void k_logits(const unsigned short* __restrict__ hbf,
                                                const float* __restrict__ Wv2,
                                                const float* __restrict__ bv2,
                                                float* __restrict__ logits,
                                                float* __restrict__ bsm,
                                                float* __restrict__ bss) {
    constexpr int PITCH = 136;
    __shared__ __align__(16) unsigned short Bs[64 * PITCH];   // 17 KB
    __shared__ float sm_[4][16], ss_[4][16];
    const int tid = threadIdx.x;
    const int lane = tid & 63, wave = tid >> 6;
    const int g = lane >> 4, c = lane & 15;
    const int wm = wave >> 1, wn = wave & 1;
    const long v0 = (long)blockIdx.x * 64;
    const bool tail = (v0 + 64 > VV);

    const int vg = tid & 15, kr = tid >> 4;

    f32x4 acc[2];
    acc[0] = (f32x4){0.f, 0.f, 0.f, 0.f};
    acc[1] = (f32x4){0.f, 0.f, 0.f, 0.f};
    const int sxr = (c & 7) << 3;

    f32x4 wa[4], wb[4];
    #pragma unroll
    for (int pi = 0; pi < 4; ++pi) {
        const int ka = kr * 8 + pi * 2;
        if (!tail) {
            wa[pi] = *(const f32x4*)&Wv2[(long)ka * VV + v0 + vg * 4];
            wb[pi] = *(const f32x4*)&Wv2[(long)(ka + 1) * VV + v0 + vg * 4];
        } else {
            #pragma unroll
            for (int j = 0; j < 4; j++) {
                long v = v0 + vg * 4 + j;
                long vs = (v < VV) ? v : (VV - 1);
                wa[pi][j] = Wv2[(long)ka * VV + vs];
                wb[pi][j] = Wv2[(long)(ka + 1) * VV + vs];
            }
        }
    }
    #pragma unroll
    for (int kt = 0; kt < 4; ++kt) {
        const int k0 = kt * 128;
        __syncthreads();
        #pragma unroll
        for (int pi = 0; pi < 4; ++pi) {
            #pragma unroll
            for (int j = 0; j < 4; j++) {
                int vl = vg * 4 + j;
                int ks = (kr * 8 + pi * 2) ^ ((vl & 7) << 3);
                unsigned int pack = (unsigned int)f2bf(wa[pi][j]) | ((unsigned int)f2bf(wb[pi][j]) << 16);
                *(unsigned int*)&Bs[vl * PITCH + ks] = pack;
            }
        }
        if (kt < 3) {
            const int k1 = (kt + 1) * 128;
            #pragma unroll
            for (int pi = 0; pi < 4; ++pi) {
                const int ka = k1 + kr * 8 + pi * 2;
                if (!tail) {
                    wa[pi] = *(const f32x4*)&Wv2[(long)ka * VV + v0 + vg * 4];
                    wb[pi] = *(const f32x4*)&Wv2[(long)(ka + 1) * VV + v0 + vg * 4];
                } else {
                    #pragma unroll
                    for (int j = 0; j < 4; j++) {
                        long v = v0 + vg * 4 + j;
                        long vs = (v < VV) ? v : (VV - 1);
                        wa[pi][j] = Wv2[(long)ka * VV + vs];
                        wb[pi][j] = Wv2[(long)(ka + 1) * VV + vs];
                    }
                }
            }
        }
        __syncthreads();
        #pragma unroll
        for (int kk = 0; kk < 4; ++kk) {
            const int koff = kk * 32 + g * 8;
            const int kse = koff ^ sxr;
            s16x8 af = *(const s16x8*)&hbf[(wm * 16 + c) * 512 + k0 + koff];
            s16x8 bf0 = *(const s16x8*)&Bs[(wn * 32 + c) * PITCH + kse];
            s16x8 bf1 = *(const s16x8*)&Bs[(wn * 32 + 16 + c) * PITCH + kse];
            acc[0] = __builtin_amdgcn_mfma_f32_16x16x32_bf16(af, bf0, acc[0], 0, 0, 0);
            acc[1] = __builtin_amdgcn_mfma_f32_16x16x32_bf16(af, bf1, acc[1], 0, 0, 0);
        }
    }
    float lv[2][4];
    #pragma unroll
    for (int j = 0; j < 2; j++) {
        long v = v0 + wn * 32 + j * 16 + c;
        bool valid = (v < VV);
        float bvv = valid ? bv2[v] : 0.f;
        #pragma unroll
        for (int r = 0; r < 4; r++) {
            float val = acc[j][r] + bvv;
            if (valid) {
                int b = wm * 16 + g * 4 + r;
                logits[(long)b * VV + v] = val;
                lv[j][r] = val;
            } else {
                lv[j][r] = -1e30f;
            }
        }
    }
    float mrow[4], srow[4];
    #pragma unroll
    for (int r = 0; r < 4; r++) {
        float m = fmaxf(lv[0][r], lv[1][r]);
        m = fmaxf(m, __shfl_xor(m, 1)); m = fmaxf(m, __shfl_xor(m, 2));
        m = fmaxf(m, __shfl_xor(m, 4)); m = fmaxf(m, __shfl_xor(m, 8));
        float s = __expf(lv[0][r] - m) + __expf(lv[1][r] - m);
        s += __shfl_xor(s, 1); s += __shfl_xor(s, 2);
        s += __shfl_xor(s, 4); s += __shfl_xor(s, 8);
        mrow[r] = m; srow[r] = s;
    }
    if (c == 0) {
        #pragma unroll
        for (int r = 0; r < 4; r++) { sm_[wave][g * 4 + r] = mrow[r]; ss_[wave][g * 4 + r] = srow[r]; }
    }
    __syncthreads();
    if (tid < 32) {
        int b = tid;
        int w0 = (b >> 4) * 2, ridx = b & 15;
        float mA = sm_[w0][ridx], mB = sm_[w0 + 1][ridx];
        float sA = ss_[w0][ridx], sB = ss_[w0 + 1][ridx];
        float m = fmaxf(mA, mB);
        float s = sA * __expf(mA - m) + sB * __expf(mB - m);
        bsm[(long)b * NBLK + blockIdx.x] = m;
        bss[(long)b * NBLK + blockIdx.x] = s;
    }
}

// ---------------------------------------------------------------- K8: stats combine + vocab write + slice-owned scatter
__global__ __launch_bounds__(512) void k_vocab(
    const float* __restrict__ logits, const float* __restrict__ bsm,
    const float* __restrict__ bss, const float* __restrict__ pgen,
    const float* __restrict__ extraz, const float* __restrict__ att,
    const int* __restrict__ eiv, float* __restrict__ out0) {
    int b = blockIdx.x;
    int v0 = blockIdx.y * 2048;
    int tid = threadIdx.x;
    __shared__ float smm[8], sms[8], fin[2];
    float m = -1e30f, s = 0.f;
    #pragma unroll
    for (int it = 0; it < 2; ++it) {
        int i = tid + it * 512;
        if (i < NBLK) {
            float mi = bsm[(long)b * NBLK + i], si = bss[(long)b * NBLK + i];
            float nm = fmaxf(m, mi);
            s = s * __expf(m - nm) + si * __expf(mi - nm);
            m = nm;
        }
    }
    for (int o = 32; o; o >>= 1) {
        float m2 = __shfl_xor(m, o), s2 = __shfl_xor(s, o);
        float nm = fmaxf(m, m2);
        s = s * __expf(m - nm) + s2 * __expf(m2 - nm);
        m = nm;
    }
    if ((tid & 63) == 0) { smm[tid >> 6] = m; sms[tid >> 6] = s; }
    __syncthreads();
    if (tid == 0) {
        float fm = smm[0], fs = sms[0];
        #pragma unroll
        for (int i = 1; i < 8; i++) {
            float nm = fmaxf(fm, smm[i]);
            fs = fs * __expf(fm - nm) + sms[i] * __expf(smm[i] - nm);
            fm = nm;
        }
        fin[0] = fm; fin[1] = pgen[b] / fs;
    }
    __syncthreads();
    float mx = fin[0], inv = fin[1];
    float pg = pgen[b];
    const float* lr = logits + (long)b * VV;
    float* orow = out0 + (long)b * VE;
    #pragma unroll
    for (int i = 0; i < 4; i++) {
        int v = v0 + i * 512 + tid;
        if (v < VV)      orow[v] = __expf(lr[v] - mx) * inv;
        else if (v < VE) orow[v] = extraz[b * EXTRA + (v - VV)];
    }
    __syncthreads();
    int vend = v0 + 2048;
    #pragma unroll
    for (int it = 0; it < 2; ++it) {
        int t = tid + it * 512;
        int tgt = eiv[b * TT + t];
        if (tgt >= v0 && tgt < vend) {
            float a = (1.f - pg) * att[b * TT + t];
            atomicAdd(orow + tgt, a);
        }
    }
}

// ================================================================ host
extern "C" void kernel_launch(void* const* d_in, const int* in_sizes, int n_in,
                              void* d_out, int out_size, void* d_ws, size_t ws_size,
                              hipStream_t stream) {
    const int*   dec_in = (const int*)d_in[0];
    const float* h0     = (const float*)d_in[1];
    const float* c0     = (const float*)d_in[2];
    const float* enc    = (const float*)d_in[3];
    const float* mask   = (const float*)d_in[4];
    const float* pcv    = (const float*)d_in[5];
    const float* cov    = (const float*)d_in[6];
    const float* extraz = (const float*)d_in[7];
    const int*   eiv    = (const int*)d_in[8];
    /* d_in[9] = step (unused, training path) */
    const float* embt   = (const float*)d_in[10];
    const float* Wgx    = (const float*)d_in[11];
    const float* bgx    = (const float*)d_in[12];
    const float* Wih    = (const float*)d_in[13];
    const float* Whh    = (const float*)d_in[14];
    const float* bih    = (const float*)d_in[15];
    const float* bhh    = (const float*)d_in[16];
    const float* Wh     = (const float*)d_in[17];
    const float* Wc     = (const float*)d_in[18];
    const float* Ws     = (const float*)d_in[19];
    const float* bs     = (const float*)d_in[20];
    const float* vv     = (const float*)d_in[21];
    const float* Wpg    = (const float*)d_in[22];
    const float* bpg    = (const float*)d_in[23];
    const float* Wv1    = (const float*)d_in[24];
    const float* bv1    = (const float*)d_in[25];
    const float* Wv2    = (const float*)d_in[26];
    const float* bv2    = (const float*)d_in[27];

    float* out = (float*)d_out;
    float* out_vd  = out;
    float* out_h1  = out + (long)BB * VE;
    float* out_c1  = out_h1 + BB * DD;
    float* out_ctx = out_c1 + BB * DD;
    float* out_att = out_ctx + BB * D2;
    float* out_cov = out_att + BB * TT;

    char* p = (char*)d_ws;
    unsigned short* whtswz = (unsigned short*)p; p += (size_t)D2 * D2 * 2;      // 2 MB
    float* xbuf    = (float*)p;  p += (size_t)BB * EE * 4;
    float* dechat  = (float*)p;  p += (size_t)BB * D2 * 4;
    float* decfeat = (float*)p;  p += (size_t)BB * D2 * 4;
    float* scorep  = (float*)p;  p += (size_t)4 * MM * 4;                        // 512 KB
    float* pgen    = (float*)p;  p += 256;
    unsigned short* hbf = (unsigned short*)p; p += (size_t)BB * DD * 2 + 256;    // 32 KB
    float* bsm     = (float*)p;  p += (size_t)BB * NBLK * 4;                     // 100 KB
    float* bss     = (float*)p;  p += (size_t)BB * NBLK * 4;                     // 100 KB
    float* ctxpart = (float*)p;  p += (size_t)32 * BB * D2 * 4;                  // 4 MB
    float* logits  = (float*)p;  p += (size_t)BB * VV * 4;                       // 6.43 MB
    unsigned short* encswz = (unsigned short*)p; p += (size_t)MM * D2 * 2;       // 67.1 MB

    k_prep<<<1152 + 16384, 256, 0, stream>>>(Wh, enc, dec_in, pcv, embt, Wgx, bgx,
                                             whtswz, encswz, xbuf);
    k_lstm<<<dim3(BB, 8), 512, 0, stream>>>(xbuf, h0, c0, Wih, Whh, bih, bhh, out_h1, out_c1, dechat);
    k_decfeat<<<dim3(BB, 16), 512, 0, stream>>>(dechat, Ws, bs, decfeat);
    k_scores<<<1024, 512, 0, stream>>>(encswz, whtswz, decfeat, cov, Wc, vv, scorep);
    k_ctx<<<dim3(BB, 16), 256, 0, stream>>>(scorep, mask, cov, encswz, out_att, out_cov, ctxpart);
    k_hidden2<<<dim3(BB, 8), 512, 0, stream>>>(ctxpart, out_h1, dechat, xbuf, Wpg, bpg,
                                               Wv1, bv1, out_ctx, pgen, hbf);
    k_logits<<<NBLK, 256, 0, stream>>>(hbf, Wv2, bv2, logits, bsm, bss);
    k_vocab<<<dim3(BB, 25), 512, 0, stream>>>(logits, bsm, bss, pgen, extraz, out_att, eiv, out_vd);
}